// Round 12
// baseline (805.828 us; speedup 1.0000x reference)
//
#include <hip/hip_runtime.h>

// ---------------------------------------------------------------------------
// VariLengthInputLayer: fused multi-modality QKV + 4x4 attention + FC + LN
//   K1: merged f32->bf16 convert (one dispatch; nt input loads)
//   K2: grouped QKV GEMM, 256x256 tile, BK=64:
//       A: global_load_lds -> 4-deep rotating LDS (A-only, 128 KiB), swizzled
//       B: DIRECT global->register fragments (K-contiguous 16B loads),
//          ping-pong prefetch 1 K-tile ahead  [LDS port relief: 256->160KB/Kt]
//       1 barrier/K-tile; manual vmcnt certs A staging cross-wave
//   K3: attention: 4 (b,h) pairs per wave, 16-lane groups (nt qkv loads)
//   K4: FC GEMM (same engine) + bias + residual -> pre-LN bf16
//   K5: LayerNorm(1024, bf16 in) -> d_out
// ---------------------------------------------------------------------------

typedef unsigned short u16;
typedef short short8 __attribute__((ext_vector_type(8)));
typedef unsigned short u16x4 __attribute__((ext_vector_type(4)));
typedef float f32x4 __attribute__((ext_vector_type(4)));

__device__ __forceinline__ u16 f2bf(float f) {
  unsigned u = __builtin_bit_cast(unsigned, f);
  u += 0x7FFFu + ((u >> 16) & 1u);  // RNE
  return (u16)(u >> 16);
}
__device__ __forceinline__ float bf2f(u16 s) {
  return __builtin_bit_cast(float, ((unsigned)s) << 16);
}

__device__ __forceinline__ void gload16(const u16* g, u16* l) {
  __builtin_amdgcn_global_load_lds(
      (const __attribute__((address_space(1))) void*)g,
      (__attribute__((address_space(3))) void*)l, 16, 0, 0);
}

#define CFENCE asm volatile("" ::: "memory")

// --------------------------- merged f32 -> bf16 convert --------------------
struct CArgs {
  const float* src[14];
  unsigned long dst[14];
  int blk0[14];
  int n4[14];
};

__global__ __launch_bounds__(256) void convall(CArgs a, u16* __restrict__ wsb) {
  int blk = blockIdx.x;
  int s = 0;
#pragma unroll
  for (int i = 1; i < 14; ++i) s = (blk >= a.blk0[i]) ? i : s;
  int li = (blk - a.blk0[s]) * 256 + threadIdx.x;
  if (li < a.n4[s]) {
    f32x4 v = __builtin_nontemporal_load((const f32x4*)a.src[s] + li);
    u16x4 o;
    o.x = f2bf(v.x); o.y = f2bf(v.y); o.z = f2bf(v.z); o.w = f2bf(v.w);
    *((u16x4*)(wsb + a.dst[s]) + li) = o;
  }
}

// --------------------------- 256^2 GEMM, B-direct-to-reg -------------------
// C = A @ B^T.  A [M x K] bf16 (row stride lda), B [N x K] bf16 (K contig).
// 512 threads = 8 waves (2M x 4N); per-wave 128x64 out; BK=64 K-tiles.
// LDS 128 KiB = 4 rotating A-tiles (256x64), 16B-chunk XOR swizzle
//   (pc = kc ^ (rw&7); linear LDS dest + inverse-swizzled global source;
//    verified conflict-free in R8/R11).
// B never touches LDS: each frag is a contiguous 16B global load
//   B[bcol + wn*64 + ni*16 + lr][t*64 + ks*32 + lk*8 .. +8]; prefetched one
//   K-tile ahead into ping-ponged register arrays B0/B1 (static indexing).
// Body(s): stage A(s+2) [4 gload_lds]; load B(s+1) [8]; CFENCE;
//   for mi 0..7 { 2 ds_read; 8 MFMA }   (compiler schedules lgkm)
//   vmcnt(20|16) -> certs A(s+1) staging for ALL waves (pre-barrier drain);
//   barrier.
// Cert arithmetic (per-wave deterministic issue order):
//   after A(s+1)'s 4 gloads: B(s)[8] + stageA(s+2)[4 if s+2<nt] +
//   B(s+1)[8 if s+1<nt]  =>  N = 20 steady, 16 at s+2==nt.
// MODE 0: grouped QKV (seg->modality, LPT), C -> qkv bf16 ldc 12288
// MODE 1: FC, C -> bf16 pre = acc + bias + residual(qkv v-slice), ldc 1024
template <int MODE>
__global__ __launch_bounds__(512, 2)
void gemm8(const u16* __restrict__ Abase, int lda,
           const u16* __restrict__ Wbase, u16* __restrict__ Cq,
           u16* __restrict__ Cpre, const float* __restrict__ bias,
           const u16* __restrict__ resid) {
  __shared__ __align__(16) u16 lds[65536];  // 128 KiB, 4 x 32KB A tiles

  const int tid = threadIdx.x;
  const int w = tid >> 6, lane = tid & 63;
  const int lr = lane & 15, lk = lane >> 4;
  const int wm = w >> 2, wn = w & 3;

  int K, nt, bx, by, coff;
  const u16 *A, *B;
  if (MODE == 0) {
    int seg = blockIdx.x / 384;  // LPT: longest K first
    int r = blockIdx.x % 384;
    bx = r % 12; by = r / 12;
    K = 4096 >> seg; nt = 64 >> seg;
    int xo, wo, mod;
    switch (seg) {
      case 0:  xo = 3584; wo = 11010048; mod = 3; break;
      case 1:  xo = 0;    wo = 0;        mod = 0; break;
      case 2:  xo = 2048; wo = 6291456;  mod = 1; break;
      default: xo = 3072; wo = 9437184;  mod = 2; break;
    }
    coff = mod * 3072;
    A = Abase + xo;
    B = Wbase + wo;
  } else {
    bx = blockIdx.x & 3; by = blockIdx.x >> 2;
    K = 1024; nt = 16; coff = 0;
    A = Abase; B = Wbase;
  }
  const size_t brow = (size_t)by * 256;
  const int bcol = bx * 256;
  const u16* Ab = A + brow * (size_t)lda;
  const u16* Bb = B + (size_t)bcol * (size_t)K;

  // per-wave B row pointers (4 rows, one per ni)
  const u16* bp0 = Bb + (size_t)(wn * 64 + 0 * 16 + lr) * (size_t)K + lk * 8;
  const u16* bp1 = Bb + (size_t)(wn * 64 + 1 * 16 + lr) * (size_t)K + lk * 8;
  const u16* bp2 = Bb + (size_t)(wn * 64 + 2 * 16 + lr) * (size_t)K + lk * 8;
  const u16* bp3 = Bb + (size_t)(wn * 64 + 3 * 16 + lr) * (size_t)K + lk * 8;

  f32x4 acc[8][4];
#pragma unroll
  for (int i = 0; i < 8; ++i)
#pragma unroll
    for (int j = 0; j < 4; ++j) acc[i][j] = (f32x4){0.f, 0.f, 0.f, 0.f};

  // stage full 256x64 A tile: 4 gload16/thread, linear LDS dest,
  // inverse-swizzled global source
  auto stageA = [&](int p) {
    const int base = (p & 3) * 32768;  // bytes
    const int k0 = p * 64;
#pragma unroll
    for (int l = 0; l < 4; ++l) {
      int s = l * 8192 + tid * 16;           // byte slot in tile
      int rw = s >> 7;                       // tile row 0..255
      int ck = ((s >> 4) & 7) ^ (rw & 7);    // logical k-chunk at this slot
      gload16(Ab + (size_t)rw * lda + k0 + ck * 8, &lds[(base + s) >> 1]);
    }
  };

  auto loadB = [&](int t, short8* dst) {  // dst[ni*2+ks], 8 frags
    const int ko = t * 64;
#pragma unroll
    for (int ks = 0; ks < 2; ++ks) {
      dst[0 * 2 + ks] = *(const short8*)(bp0 + ko + ks * 32);
      dst[1 * 2 + ks] = *(const short8*)(bp1 + ko + ks * 32);
      dst[2 * 2 + ks] = *(const short8*)(bp2 + ko + ks * 32);
      dst[3 * 2 + ks] = *(const short8*)(bp3 + ko + ks * 32);
    }
  };

  auto body = [&](int s, short8* Bc, short8* Bn) {
    if (s + 2 < nt) stageA(s + 2);
    if (s + 1 < nt) loadB(s + 1, Bn);
    CFENCE;  // keep stage/B-prefetch issued before compute
    const u16* lp = lds + ((s & 3) * 32768 >> 1);
#pragma unroll
    for (int mi = 0; mi < 8; ++mi) {
      const int rw = wm * 128 + mi * 16 + lr;
      const u16* rp = lp + rw * 64;
      short8 a0 = *(const short8*)(rp + ((0 * 4 + lk) ^ (rw & 7)) * 8);
      short8 a1 = *(const short8*)(rp + ((1 * 4 + lk) ^ (rw & 7)) * 8);
#pragma unroll
      for (int ni = 0; ni < 4; ++ni)
        acc[mi][ni] = __builtin_amdgcn_mfma_f32_16x16x32_bf16(
            a0, Bc[ni * 2 + 0], acc[mi][ni], 0, 0, 0);
#pragma unroll
      for (int ni = 0; ni < 4; ++ni)
        acc[mi][ni] = __builtin_amdgcn_mfma_f32_16x16x32_bf16(
            a1, Bc[ni * 2 + 1], acc[mi][ni], 0, 0, 0);
    }
    CFENCE;
    // cert A(s+1) for every wave's next-body ds_reads (drain BEFORE barrier)
    if (s + 2 < nt) {
      asm volatile("s_waitcnt vmcnt(20)" ::: "memory");
      __builtin_amdgcn_s_barrier();
    } else if (s + 1 < nt) {
      asm volatile("s_waitcnt vmcnt(16)" ::: "memory");
      __builtin_amdgcn_s_barrier();
    }
    CFENCE;
  };

  short8 B0[8], B1[8];
  // prologue: stage A(0), A(1); load B(0); drain; barrier
  stageA(0); stageA(1);
  loadB(0, B0);
  asm volatile("s_waitcnt vmcnt(0)" ::: "memory");
  __builtin_amdgcn_s_barrier();
  CFENCE;

#pragma unroll 1
  for (int t = 0; t < nt; t += 2) {  // nt even (8/16/32/64)
    body(t, B0, B1);
    body(t + 1, B1, B0);
  }

  // epilogue: C/D layout col=lane&15, row=(lane>>4)*4+j
  if (MODE == 0) {
#pragma unroll
    for (int mi = 0; mi < 8; ++mi)
#pragma unroll
      for (int ni = 0; ni < 4; ++ni) {
        const int c = coff + bcol + wn * 64 + ni * 16 + lr;
#pragma unroll
        for (int j = 0; j < 4; ++j) {
          size_t r = brow + wm * 128 + mi * 16 + lk * 4 + j;
          Cq[r * 12288 + c] = f2bf(acc[mi][ni][j]);
        }
      }
  } else {
#pragma unroll
    for (int mi = 0; mi < 8; ++mi)
#pragma unroll
      for (int ni = 0; ni < 4; ++ni) {
        const int c = bcol + wn * 64 + ni * 16 + lr;
        const float bs = bias[c];
#pragma unroll
        for (int j = 0; j < 4; ++j) {
          size_t r = brow + wm * 128 + mi * 16 + lk * 4 + j;
          size_t ridx = (r >> 2) * 12288 + (r & 3) * 3072 + 2048 + c;
          Cpre[r * 1024 + c] = f2bf(acc[mi][ni][j] + bs + bf2f(resid[ridx]));
        }
      }
  }
}

// --------------------------- attention ------------------------------------
__global__ __launch_bounds__(256) void attn_k(const u16* __restrict__ qkv,
                                              u16* __restrict__ ctxb,
                                              float* __restrict__ attn_out) {
  const int tid = threadIdx.x;
  const int l = tid & 63;
  const int wg = blockIdx.x * 4 + (tid >> 6);
  const int b = wg >> 2;
  const int h0 = (wg & 3) << 2;
  const size_t base = (size_t)b * 12288 + h0 * 64 + l * 4;

  float q[4][4], k[4][4], v[4][4];
#pragma unroll
  for (int m = 0; m < 4; ++m) {
    u16x4 uq = __builtin_nontemporal_load((const u16x4*)(qkv + base + m * 3072));
    u16x4 uk = __builtin_nontemporal_load((const u16x4*)(qkv + base + m * 3072 + 1024));
    u16x4 uv = __builtin_nontemporal_load((const u16x4*)(qkv + base + m * 3072 + 2048));
    q[m][0] = bf2f(uq.x); q[m][1] = bf2f(uq.y); q[m][2] = bf2f(uq.z); q[m][3] = bf2f(uq.w);
    k[m][0] = bf2f(uk.x); k[m][1] = bf2f(uk.y); k[m][2] = bf2f(uk.z); k[m][3] = bf2f(uk.w);
    v[m][0] = bf2f(uv.x); v[m][1] = bf2f(uv.y); v[m][2] = bf2f(uv.z); v[m][3] = bf2f(uv.w);
  }

  float s[16];
#pragma unroll
  for (int i = 0; i < 4; ++i)
#pragma unroll
    for (int j = 0; j < 4; ++j) {
      float acc = q[i][0] * k[j][0];
      acc += q[i][1] * k[j][1];
      acc += q[i][2] * k[j][2];
      acc += q[i][3] * k[j][3];
      s[i * 4 + j] = acc;
    }
#pragma unroll
  for (int off = 1; off < 16; off <<= 1) {
#pragma unroll
    for (int t = 0; t < 16; ++t) s[t] += __shfl_xor(s[t], off);
  }

  float a[16];
#pragma unroll
  for (int i = 0; i < 4; ++i) {
    float s0 = s[i * 4 + 0] * 0.125f, s1 = s[i * 4 + 1] * 0.125f;
    float s2 = s[i * 4 + 2] * 0.125f, s3 = s[i * 4 + 3] * 0.125f;
    float m = fmaxf(fmaxf(s0, s1), fmaxf(s2, s3));
    float e0 = __expf(s0 - m), e1 = __expf(s1 - m);
    float e2 = __expf(s2 - m), e3 = __expf(s3 - m);
    float inv = 1.0f / (e0 + e1 + e2 + e3);
    a[i * 4 + 0] = e0 * inv; a[i * 4 + 1] = e1 * inv;
    a[i * 4 + 2] = e2 * inv; a[i * 4 + 3] = e3 * inv;
  }

#pragma unroll
  for (int i = 0; i < 4; ++i) {
    float c0 = a[i*4+0]*v[0][0] + a[i*4+1]*v[1][0] + a[i*4+2]*v[2][0] + a[i*4+3]*v[3][0];
    float c1 = a[i*4+0]*v[0][1] + a[i*4+1]*v[1][1] + a[i*4+2]*v[2][1] + a[i*4+3]*v[3][1];
    float c2 = a[i*4+0]*v[0][2] + a[i*4+1]*v[1][2] + a[i*4+2]*v[2][2] + a[i*4+3]*v[3][2];
    float c3 = a[i*4+0]*v[0][3] + a[i*4+1]*v[1][3] + a[i*4+2]*v[2][3] + a[i*4+3]*v[3][3];
    u16x4 o;
    o.x = f2bf(c0); o.y = f2bf(c1); o.z = f2bf(c2); o.w = f2bf(c3);
    *(u16x4*)(ctxb + (size_t)b * 4096 + i * 1024 + h0 * 64 + l * 4) = o;
  }

  int sel = l & 15;
  float val = a[0];
#pragma unroll
  for (int t = 1; t < 16; ++t) val = (sel == t) ? a[t] : val;
  __builtin_nontemporal_store(val, &attn_out[(size_t)b * 256 + h0 * 16 + l]);
}

// --------------------------- layernorm (bf16 in) ----------------------------
__global__ __launch_bounds__(256) void ln_k(const u16* __restrict__ pre,
                                            const float* __restrict__ g,
                                            const float* __restrict__ b,
                                            float* __restrict__ out) {
  int row = blockIdx.x;
  int tid = threadIdx.x;
  u16x4 u = __builtin_nontemporal_load(
      (const u16x4*)(pre + (size_t)row * 1024 + tid * 4));
  float x0 = bf2f(u.x), x1 = bf2f(u.y), x2 = bf2f(u.z), x3 = bf2f(u.w);
  float s = x0 + x1 + x2 + x3;
  float s2 = x0 * x0 + x1 * x1 + x2 * x2 + x3 * x3;
#pragma unroll
  for (int off = 32; off; off >>= 1) {
    s += __shfl_xor(s, off);
    s2 += __shfl_xor(s2, off);
  }
  __shared__ float r1[4], r2[4];
  int w = tid >> 6, lane = tid & 63;
  if (lane == 0) { r1[w] = s; r2[w] = s2; }
  __syncthreads();
  s = r1[0] + r1[1] + r1[2] + r1[3];
  s2 = r2[0] + r2[1] + r2[2] + r2[3];
  float mu = s * (1.0f / 1024.0f);
  float inv = rsqrtf(s2 * (1.0f / 1024.0f) - mu * mu + 1e-6f);
  float4 gv = *(const float4*)(g + tid * 4);
  float4 bv = *(const float4*)(b + tid * 4);
  f32x4 o;
  o.x = (x0 - mu) * inv * gv.x + bv.x;
  o.y = (x1 - mu) * inv * gv.y + bv.y;
  o.z = (x2 - mu) * inv * gv.z + bv.z;
  o.w = (x3 - mu) * inv * gv.w + bv.w;
  __builtin_nontemporal_store(o, (f32x4*)(out + (size_t)row * 1024 + tid * 4));
}

// ---------------------------------------------------------------------------
extern "C" void kernel_launch(void* const* d_in, const int* in_sizes, int n_in,
                              void* d_out, int out_size, void* d_ws,
                              size_t ws_size, hipStream_t stream) {
  const float* fcb = (const float*)d_in[14];
  const float* lng = (const float*)d_in[15];
  const float* lnb = (const float*)d_in[16];

  u16* wsb = (u16*)d_ws;
  u16* xb = wsb;                 // 62,914,560
  u16* wb = xb + 62914560;       // 24,641,536
  u16* qkv = wb + 24641536;      // 100,663,296  [b][mod][q|k|v][1024]
  u16* ctxb = qkv + 100663296;   // 33,554,432
  u16* pre = wsb;                // bf16 32768x1024 = 64MB, overlays dead xb
  float* outp = (float*)d_out;
  float* attn_out = outp + 33554432;

  static const unsigned long woff[13] = {
      0,        2097152,  4194304,   // mod0 K=2048 (q,k,v)
      6291456,  7340032,  8388608,   // mod1 K=1024
      9437184,  9961472,  10485760,  // mod2 K=512
      11010048, 15204352, 19398656,  // mod3 K=4096
      23592960};                     // fc
  static const int wn4[13] = {524288, 524288, 524288, 262144, 262144, 262144,
                              131072, 131072, 131072, 1048576, 1048576, 1048576,
                              262144};

  // K1: one conversion dispatch
  CArgs ca;
  ca.src[0] = (const float*)d_in[0];
  ca.dst[0] = 0;
  ca.n4[0] = 62914560 / 4;
  ca.blk0[0] = 0;
  int nb = ca.n4[0] / 256;
  for (int i = 0; i < 13; ++i) {
    ca.src[i + 1] = (const float*)d_in[1 + i];
    ca.dst[i + 1] = 62914560ul + woff[i];
    ca.n4[i + 1] = wn4[i];
    ca.blk0[i + 1] = nb;
    nb += (wn4[i] + 255) / 256;
  }
  convall<<<dim3(nb), 256, 0, stream>>>(ca, wsb);

  // K2: grouped QKV projections, one dispatch (4 segs x 384 blocks, LPT)
  gemm8<0><<<dim3(1536), 512, 0, stream>>>(xb, 7680, wb, qkv, nullptr, nullptr,
                                           nullptr);

  // K3: attention
  attn_k<<<dim3(8192), 256, 0, stream>>>(qkv, ctxb, attn_out);

  // K4: FC + bias + residual -> pre-LN bf16
  gemm8<1><<<dim3(512), 512, 0, stream>>>(ctxb, 1024, wb + 23592960, nullptr,
                                          pre, fcb, qkv);

  // K5: LayerNorm -> out
  ln_k<<<dim3(32768), 256, 0, stream>>>(pre, lng, lnb, outp);
}

// Round 13
// 599.584 us; speedup vs baseline: 1.3440x; 1.3440x over previous
//
#include <hip/hip_runtime.h>

// ---------------------------------------------------------------------------
// VariLengthInputLayer: fused multi-modality QKV + 4x4 attention + FC + LN
//   K1: merged f32->bf16 convert (one dispatch; nt input loads)
//   K2: grouped QKV GEMM, 256x256 tile, BK=64, 4-phase cert template,
//       16x16x32 MFMA (conflict-free swizzle), paired staging P1/P3,
//       counted vmcnt(4) at end-P1/end-P4, 2D XCD-chunked block mapping
//       (each XCD owns 16by x 3bx -> A panels L2-resident, B x4 reuse)
//   K3: attention: 4 (b,h) pairs per wave, 16-lane groups (nt qkv loads)
//   K4: FC GEMM (same engine) + bias + residual -> pre-LN bf16
//   K5: LayerNorm(1024, bf16 in) -> d_out
// ---------------------------------------------------------------------------

typedef unsigned short u16;
typedef short short8 __attribute__((ext_vector_type(8)));
typedef unsigned short u16x4 __attribute__((ext_vector_type(4)));
typedef float f32x4 __attribute__((ext_vector_type(4)));

__device__ __forceinline__ u16 f2bf(float f) {
  unsigned u = __builtin_bit_cast(unsigned, f);
  u += 0x7FFFu + ((u >> 16) & 1u);  // RNE
  return (u16)(u >> 16);
}
__device__ __forceinline__ float bf2f(u16 s) {
  return __builtin_bit_cast(float, ((unsigned)s) << 16);
}

__device__ __forceinline__ void gload16(const u16* g, u16* l) {
  __builtin_amdgcn_global_load_lds(
      (const __attribute__((address_space(1))) void*)g,
      (__attribute__((address_space(3))) void*)l, 16, 0, 0);
}

#define CFENCE asm volatile("" ::: "memory")

// --------------------------- merged f32 -> bf16 convert --------------------
struct CArgs {
  const float* src[14];
  unsigned long dst[14];
  int blk0[14];
  int n4[14];
};

__global__ __launch_bounds__(256) void convall(CArgs a, u16* __restrict__ wsb) {
  int blk = blockIdx.x;
  int s = 0;
#pragma unroll
  for (int i = 1; i < 14; ++i) s = (blk >= a.blk0[i]) ? i : s;
  int li = (blk - a.blk0[s]) * 256 + threadIdx.x;
  if (li < a.n4[s]) {
    f32x4 v = __builtin_nontemporal_load((const f32x4*)a.src[s] + li);
    u16x4 o;
    o.x = f2bf(v.x); o.y = f2bf(v.y); o.z = f2bf(v.z); o.w = f2bf(v.w);
    *((u16x4*)(wsb + a.dst[s]) + li) = o;  // plain store: GEMM re-reads this
  }
}

// --------------------------- 256^2 4-phase GEMM (16x16 MFMA) ---------------
// C = A @ B^T.  A [M x K] bf16 (row stride lda), B [N x K] bf16 (K contig).
// 512 threads = 8 waves (2M x 4N); per-wave 128x64 out; BK=64 K-tiles.
// LDS 128 KiB: buf(t&1) { A: 2 halves (row bit6), B: 2 halves (col bit5) }.
//   16B-chunk swizzle pc = kc ^ (rw&7); staging writes linear LDS dest from
//   inverse-swizzled global source; reads apply the same XOR. Quarter-wave
//   has 2 lanes/slot -> conflict-free (verified R8/R11: BANK_CONFLICT=0).
// Phases per K-tile t:
//   P1: read A-L[8] B-L[4]; stage A-L+B-L(t+1); bar; lgkm0; Q00;
//       vmcnt(4) [certs B-H,A-H(t)]; bar
//   P2: read B-H[4];                            bar; lgkm0; Q01; bar
//   P3: read A-H[8]; stage B-H+A-H(t+1);        bar; lgkm0; Q11; bar
//   P4: (no reads);                             bar;        Q10;
//       vmcnt(4) [certs A-L,B-L(t+1)]; bar
// Block mapping (MODE 0): hw assigns xcd = blockIdx%8. Each XCD owns a
//   16by x 3bx chunk per segment (384%8==0 -> bijective): A panels (2MB)
//   become XCD-L2-resident (3 consecutive slots share one), B panels are
//   fetched by at most 4 XCDs. Minimizes 126MB*Nx + 47MB*Ny at NxNy=8.
// MODE 0: grouped QKV (seg->modality, LPT), C -> qkv bf16 ldc 12288
// MODE 1: FC, C -> bf16 pre = acc + bias + residual(qkv v-slice), ldc 1024
template <int MODE>
__global__ __launch_bounds__(512, 2)
void gemm8(const u16* __restrict__ Abase, int lda,
           const u16* __restrict__ Wbase, u16* __restrict__ Cq,
           u16* __restrict__ Cpre, const float* __restrict__ bias,
           const u16* __restrict__ resid) {
  __shared__ __align__(16) u16 lds[65536];  // 128 KiB

  const int tid = threadIdx.x;
  const int w = tid >> 6, lane = tid & 63;
  const int lr = lane & 15, lk = lane >> 4;
  const int wm = w >> 2, wn = w & 3;

  int K, nt, bx, by, coff;
  const u16 *A, *B;
  if (MODE == 0) {
    int seg = blockIdx.x / 384;  // LPT: longest K first
    int r = blockIdx.x % 384;
    // 2D XCD chunking: xcd = r%8 (hw round-robin, 384%8==0);
    // xcd grid = 2 by-groups x 4 bx-groups; chunk = 16by x 3bx, bx fastest
    int xcd = r & 7;
    int slot = r >> 3;               // 0..47
    by = (xcd >> 2) * 16 + slot / 3;
    bx = (xcd & 3) * 3 + slot % 3;
    K = 4096 >> seg; nt = 64 >> seg;
    int xo, wo, mod;
    switch (seg) {
      case 0:  xo = 3584; wo = 11010048; mod = 3; break;
      case 1:  xo = 0;    wo = 0;        mod = 0; break;
      case 2:  xo = 2048; wo = 6291456;  mod = 1; break;
      default: xo = 3072; wo = 9437184;  mod = 2; break;
    }
    coff = mod * 3072;
    A = Abase + xo;
    B = Wbase + wo;
  } else {
    // 512 blocks: each XCD owns 16by x 4bx (512%8==0 -> bijective)
    int xcd = blockIdx.x & 7;
    int slot = blockIdx.x >> 3;      // 0..63
    by = xcd * 16 + (slot >> 2);
    bx = slot & 3;
    K = 1024; nt = 16; coff = 0;
    A = Abase; B = Wbase;
  }
  const size_t brow = (size_t)by * 256;
  const int bcol = bx * 256;
  const u16* Ab = A + brow * (size_t)lda;
  const u16* Bb = B + (size_t)bcol * (size_t)K;

  f32x4 acc[8][4];
#pragma unroll
  for (int i = 0; i < 8; ++i)
#pragma unroll
    for (int j = 0; j < 4; ++j) acc[i][j] = (f32x4){0.f, 0.f, 0.f, 0.f};

  // ---- staging: 1 half = 16 KB = 2 x gload16/thread, linear LDS dest ----
  auto stageA = [&](int p, int half) {
    const int base = (p & 1) * 65536 + half * 16384;  // bytes
    const int k0 = p * 64;
#pragma unroll
    for (int l = 0; l < 2; ++l) {
      int s = l * 8192 + tid * 16;                  // byte slot in half
      int rw = s >> 7;                              // row-within-half
      int ck = ((s >> 4) & 7) ^ (rw & 7);           // logical k-chunk here
      int row = (rw & 63) + ((rw >> 6) << 7) + half * 64;  // tile row
      gload16(Ab + (size_t)row * lda + k0 + ck * 8, &lds[(base + s) >> 1]);
    }
  };
  auto stageB = [&](int p, int half) {
    const int base = (p & 1) * 65536 + 32768 + half * 16384;
    const int k0 = p * 64;
#pragma unroll
    for (int l = 0; l < 2; ++l) {
      int s = l * 8192 + tid * 16;
      int rw = s >> 7;
      int ck = ((s >> 4) & 7) ^ (rw & 7);
      int col = (rw & 31) + ((rw >> 5) << 6) + half * 32;  // tile col (B row)
      gload16(Bb + (size_t)col * (size_t)K + k0 + ck * 8, &lds[(base + s) >> 1]);
    }
  };

  // ---- fragment reads (swizzled), 16x16x32 operand layout ----
  auto ldA = [&](int t, int half, short8* dst) {  // dst[mi*2+ks], 8 frags
    const u16* lp = lds + (((t & 1) * 65536 + half * 16384) >> 1);
#pragma unroll
    for (int mi = 0; mi < 4; ++mi) {
      int rw = wm * 64 + mi * 16 + lr;
#pragma unroll
      for (int ks = 0; ks < 2; ++ks) {
        int pc = (ks * 4 + lk) ^ (rw & 7);
        dst[mi * 2 + ks] = *(const short8*)(lp + rw * 64 + pc * 8);
      }
    }
  };
  auto ldB = [&](int t, int half, short8* dst) {  // dst[ni*2+ks], 4 frags
    const u16* lp = lds + (((t & 1) * 65536 + 32768 + half * 16384) >> 1);
#pragma unroll
    for (int ni = 0; ni < 2; ++ni) {
      int rw = wn * 32 + ni * 16 + lr;
#pragma unroll
      for (int ks = 0; ks < 2; ++ks) {
        int pc = (ks * 4 + lk) ^ (rw & 7);
        dst[ni * 2 + ks] = *(const short8*)(lp + rw * 64 + pc * 8);
      }
    }
  };

  short8 af[8], bl[4], bh[4];
  auto MQ = [&](short8* a, short8* b, int mo, int no) {  // 16 MFMA quadrant
#pragma unroll
    for (int mi = 0; mi < 4; ++mi)
#pragma unroll
      for (int ni = 0; ni < 2; ++ni) {
        acc[mo + mi][no + ni] = __builtin_amdgcn_mfma_f32_16x16x32_bf16(
            a[mi * 2 + 0], b[ni * 2 + 0], acc[mo + mi][no + ni], 0, 0, 0);
        acc[mo + mi][no + ni] = __builtin_amdgcn_mfma_f32_16x16x32_bf16(
            a[mi * 2 + 1], b[ni * 2 + 1], acc[mo + mi][no + ni], 0, 0, 0);
      }
  };

  // prologue: stage tile 0 (A-L, B-L, B-H, A-H); cert A-L,B-L only
  stageA(0, 0); stageB(0, 0); stageB(0, 1); stageA(0, 1);
  asm volatile("s_waitcnt vmcnt(4)" ::: "memory");
  __builtin_amdgcn_s_barrier();
  CFENCE;

#pragma unroll 1
  for (int t = 0; t < nt; ++t) {
    const bool more = (t + 1 < nt);
    // -------- P1: A-L + B-L reads, stage {A-L,B-L}(t+1), Q00 ------------
    ldA(t, 0, af);
    ldB(t, 0, bl);
    if (more) { stageA(t + 1, 0); stageB(t + 1, 0); }
    CFENCE;
    __builtin_amdgcn_s_barrier();
    asm volatile("s_waitcnt lgkmcnt(0)" ::: "memory");
    __builtin_amdgcn_sched_barrier(0);
    __builtin_amdgcn_s_setprio(1);
    MQ(af, bl, 0, 0);
    __builtin_amdgcn_s_setprio(0);
    CFENCE;
    // cert B-H,A-H(t): they are the oldest 4 outstanding loads
    if (more) asm volatile("s_waitcnt vmcnt(4)" ::: "memory");
    else      asm volatile("s_waitcnt vmcnt(0)" ::: "memory");
    __builtin_amdgcn_s_barrier();
    CFENCE;
    // -------- P2: B-H reads, Q01 ----------------------------------------
    ldB(t, 1, bh);
    CFENCE;
    __builtin_amdgcn_s_barrier();
    asm volatile("s_waitcnt lgkmcnt(0)" ::: "memory");
    __builtin_amdgcn_sched_barrier(0);
    __builtin_amdgcn_s_setprio(1);
    MQ(af, bh, 0, 2);
    __builtin_amdgcn_s_setprio(0);
    CFENCE;
    __builtin_amdgcn_s_barrier();
    CFENCE;
    // -------- P3: A-H reads, stage {B-H,A-H}(t+1), Q11 ------------------
    ldA(t, 1, af);
    if (more) { stageB(t + 1, 1); stageA(t + 1, 1); }
    CFENCE;
    __builtin_amdgcn_s_barrier();
    asm volatile("s_waitcnt lgkmcnt(0)" ::: "memory");
    __builtin_amdgcn_sched_barrier(0);
    __builtin_amdgcn_s_setprio(1);
    MQ(af, bh, 4, 2);
    __builtin_amdgcn_s_setprio(0);
    CFENCE;
    __builtin_amdgcn_s_barrier();
    CFENCE;
    // -------- P4: no reads, Q10 -----------------------------------------
    __builtin_amdgcn_s_setprio(1);
    MQ(af, bl, 4, 0);
    __builtin_amdgcn_s_setprio(0);
    CFENCE;
    if (more) {
      // cert A-L,B-L(t+1): oldest 4 of the 8 outstanding loads
      asm volatile("s_waitcnt vmcnt(4)" ::: "memory");
      __builtin_amdgcn_s_barrier();
      CFENCE;
    }
  }

  // epilogue: C/D layout col=lane&15, row=(lane>>4)*4+j
  if (MODE == 0) {
#pragma unroll
    for (int mi = 0; mi < 8; ++mi)
#pragma unroll
      for (int ni = 0; ni < 4; ++ni) {
        const int c = coff + bcol + wn * 64 + ni * 16 + lr;
#pragma unroll
        for (int j = 0; j < 4; ++j) {
          size_t r = brow + wm * 128 + mi * 16 + lk * 4 + j;
          Cq[r * 12288 + c] = f2bf(acc[mi][ni][j]);
        }
      }
  } else {
#pragma unroll
    for (int mi = 0; mi < 8; ++mi)
#pragma unroll
      for (int ni = 0; ni < 4; ++ni) {
        const int c = bcol + wn * 64 + ni * 16 + lr;
        const float bs = bias[c];
#pragma unroll
        for (int j = 0; j < 4; ++j) {
          size_t r = brow + wm * 128 + mi * 16 + lk * 4 + j;
          size_t ridx = (r >> 2) * 12288 + (r & 3) * 3072 + 2048 + c;
          Cpre[r * 1024 + c] = f2bf(acc[mi][ni][j] + bs + bf2f(resid[ridx]));
        }
      }
  }
}

// --------------------------- attention ------------------------------------
__global__ __launch_bounds__(256) void attn_k(const u16* __restrict__ qkv,
                                              u16* __restrict__ ctxb,
                                              float* __restrict__ attn_out) {
  const int tid = threadIdx.x;
  const int l = tid & 63;
  const int wg = blockIdx.x * 4 + (tid >> 6);
  const int b = wg >> 2;
  const int h0 = (wg & 3) << 2;
  const size_t base = (size_t)b * 12288 + h0 * 64 + l * 4;

  float q[4][4], k[4][4], v[4][4];
#pragma unroll
  for (int m = 0; m < 4; ++m) {
    u16x4 uq = __builtin_nontemporal_load((const u16x4*)(qkv + base + m * 3072));
    u16x4 uk = __builtin_nontemporal_load((const u16x4*)(qkv + base + m * 3072 + 1024));
    u16x4 uv = __builtin_nontemporal_load((const u16x4*)(qkv + base + m * 3072 + 2048));
    q[m][0] = bf2f(uq.x); q[m][1] = bf2f(uq.y); q[m][2] = bf2f(uq.z); q[m][3] = bf2f(uq.w);
    k[m][0] = bf2f(uk.x); k[m][1] = bf2f(uk.y); k[m][2] = bf2f(uk.z); k[m][3] = bf2f(uk.w);
    v[m][0] = bf2f(uv.x); v[m][1] = bf2f(uv.y); v[m][2] = bf2f(uv.z); v[m][3] = bf2f(uv.w);
  }

  float s[16];
#pragma unroll
  for (int i = 0; i < 4; ++i)
#pragma unroll
    for (int j = 0; j < 4; ++j) {
      float acc = q[i][0] * k[j][0];
      acc += q[i][1] * k[j][1];
      acc += q[i][2] * k[j][2];
      acc += q[i][3] * k[j][3];
      s[i * 4 + j] = acc;
    }
#pragma unroll
  for (int off = 1; off < 16; off <<= 1) {
#pragma unroll
    for (int t = 0; t < 16; ++t) s[t] += __shfl_xor(s[t], off);
  }

  float a[16];
#pragma unroll
  for (int i = 0; i < 4; ++i) {
    float s0 = s[i * 4 + 0] * 0.125f, s1 = s[i * 4 + 1] * 0.125f;
    float s2 = s[i * 4 + 2] * 0.125f, s3 = s[i * 4 + 3] * 0.125f;
    float m = fmaxf(fmaxf(s0, s1), fmaxf(s2, s3));
    float e0 = __expf(s0 - m), e1 = __expf(s1 - m);
    float e2 = __expf(s2 - m), e3 = __expf(s3 - m);
    float inv = 1.0f / (e0 + e1 + e2 + e3);
    a[i * 4 + 0] = e0 * inv; a[i * 4 + 1] = e1 * inv;
    a[i * 4 + 2] = e2 * inv; a[i * 4 + 3] = e3 * inv;
  }

#pragma unroll
  for (int i = 0; i < 4; ++i) {
    float c0 = a[i*4+0]*v[0][0] + a[i*4+1]*v[1][0] + a[i*4+2]*v[2][0] + a[i*4+3]*v[3][0];
    float c1 = a[i*4+0]*v[0][1] + a[i*4+1]*v[1][1] + a[i*4+2]*v[2][1] + a[i*4+3]*v[3][1];
    float c2 = a[i*4+0]*v[0][2] + a[i*4+1]*v[1][2] + a[i*4+2]*v[2][2] + a[i*4+3]*v[3][2];
    float c3 = a[i*4+0]*v[0][3] + a[i*4+1]*v[1][3] + a[i*4+2]*v[2][3] + a[i*4+3]*v[3][3];
    u16x4 o;
    o.x = f2bf(c0); o.y = f2bf(c1); o.z = f2bf(c2); o.w = f2bf(c3);
    *(u16x4*)(ctxb + (size_t)b * 4096 + i * 1024 + h0 * 64 + l * 4) = o;
  }

  int sel = l & 15;
  float val = a[0];
#pragma unroll
  for (int t = 1; t < 16; ++t) val = (sel == t) ? a[t] : val;
  __builtin_nontemporal_store(val, &attn_out[(size_t)b * 256 + h0 * 16 + l]);
}

// --------------------------- layernorm (bf16 in) ----------------------------
__global__ __launch_bounds__(256) void ln_k(const u16* __restrict__ pre,
                                            const float* __restrict__ g,
                                            const float* __restrict__ b,
                                            float* __restrict__ out) {
  int row = blockIdx.x;
  int tid = threadIdx.x;
  u16x4 u = __builtin_nontemporal_load(
      (const u16x4*)(pre + (size_t)row * 1024 + tid * 4));
  float x0 = bf2f(u.x), x1 = bf2f(u.y), x2 = bf2f(u.z), x3 = bf2f(u.w);
  float s = x0 + x1 + x2 + x3;
  float s2 = x0 * x0 + x1 * x1 + x2 * x2 + x3 * x3;
#pragma unroll
  for (int off = 32; off; off >>= 1) {
    s += __shfl_xor(s, off);
    s2 += __shfl_xor(s2, off);
  }
  __shared__ float r1[4], r2[4];
  int w = tid >> 6, lane = tid & 63;
  if (lane == 0) { r1[w] = s; r2[w] = s2; }
  __syncthreads();
  s = r1[0] + r1[1] + r1[2] + r1[3];
  s2 = r2[0] + r2[1] + r2[2] + r2[3];
  float mu = s * (1.0f / 1024.0f);
  float inv = rsqrtf(s2 * (1.0f / 1024.0f) - mu * mu + 1e-6f);
  float4 gv = *(const float4*)(g + tid * 4);
  float4 bv = *(const float4*)(b + tid * 4);
  f32x4 o;
  o.x = (x0 - mu) * inv * gv.x + bv.x;
  o.y = (x1 - mu) * inv * gv.y + bv.y;
  o.z = (x2 - mu) * inv * gv.z + bv.z;
  o.w = (x3 - mu) * inv * gv.w + bv.w;
  __builtin_nontemporal_store(o, (f32x4*)(out + (size_t)row * 1024 + tid * 4));
}

// ---------------------------------------------------------------------------
extern "C" void kernel_launch(void* const* d_in, const int* in_sizes, int n_in,
                              void* d_out, int out_size, void* d_ws,
                              size_t ws_size, hipStream_t stream) {
  const float* fcb = (const float*)d_in[14];
  const float* lng = (const float*)d_in[15];
  const float* lnb = (const float*)d_in[16];

  u16* wsb = (u16*)d_ws;
  u16* xb = wsb;                 // 62,914,560
  u16* wb = xb + 62914560;       // 24,641,536
  u16* qkv = wb + 24641536;      // 100,663,296  [b][mod][q|k|v][1024]
  u16* ctxb = qkv + 100663296;   // 33,554,432
  u16* pre = wsb;                // bf16 32768x1024 = 64MB, overlays dead xb
  float* outp = (float*)d_out;
  float* attn_out = outp + 33554432;

  static const unsigned long woff[13] = {
      0,        2097152,  4194304,   // mod0 K=2048 (q,k,v)
      6291456,  7340032,  8388608,   // mod1 K=1024
      9437184,  9961472,  10485760,  // mod2 K=512
      11010048, 15204352, 19398656,  // mod3 K=4096
      23592960};                     // fc
  static const int wn4[13] = {524288, 524288, 524288, 262144, 262144, 262144,
                              131072, 131072, 131072, 1048576, 1048576, 1048576,
                              262144};

  // K1: one conversion dispatch
  CArgs ca;
  ca.src[0] = (const float*)d_in[0];
  ca.dst[0] = 0;
  ca.n4[0] = 62914560 / 4;
  ca.blk0[0] = 0;
  int nb = ca.n4[0] / 256;
  for (int i = 0; i < 13; ++i) {
    ca.src[i + 1] = (const float*)d_in[1 + i];
    ca.dst[i + 1] = 62914560ul + woff[i];
    ca.n4[i + 1] = wn4[i];
    ca.blk0[i + 1] = nb;
    nb += (wn4[i] + 255) / 256;
  }
  convall<<<dim3(nb), 256, 0, stream>>>(ca, wsb);

  // K2: grouped QKV projections, one dispatch (4 segs x 384 blocks, LPT)
  gemm8<0><<<dim3(1536), 512, 0, stream>>>(xb, 7680, wb, qkv, nullptr, nullptr,
                                           nullptr);

  // K3: attention
  attn_k<<<dim3(8192), 256, 0, stream>>>(qkv, ctxb, attn_out);

  // K4: FC + bias + residual -> pre-LN bf16
  gemm8<1><<<dim3(512), 512, 0, stream>>>(ctxb, 1024, wb + 23592960, nullptr,
                                          pre, fcb, qkv);

  // K5: LayerNorm -> out
  ln_k<<<dim3(32768), 256, 0, stream>>>(pre, lng, lnb, outp);
}